// Round 7
// baseline (135.650 us; speedup 1.0000x reference)
//
#include <hip/hip_runtime.h>
#include <hip/hip_cooperative_groups.h>

namespace cg = cooperative_groups;

#define KW   7
#define CIN  64
#define COUT 64
#define HH   64
#define WW   64
#define BB   4
#define HW   (HH * WW)

// Phase-B tile geometry
#define TR   16            // output rows per unit
#define SRB  (TR + 6)      // 22 staged k/v rows
#define SCW  70            // staged cols: 3 zero + 64 + 3 zero
#define SCP  74            // padded LDS row stride (dwords)

// ---------------------------------------------------------------------------
// 512 blocks x 256 threads; each block handles 2 "units" per phase.
// Unit space = 1024: phase A unit = (ptile 0..15, og 0..15, b 0..3),
//               phase B unit = (rowgrp 0..3, o 0..63, b 0..3).
// Phase A: R2's proven projection (thread = 1 pixel x 4 channels, no halo
//          recompute). Padded k/v positions are exactly 0 (1x1 conv of zero
//          padding, no bias) -> phase B synthesizes zeros.
// Phase B: unit = one (b,o) plane x 16 rows; k/v staged in 22x74 LDS tile
//          with zero borders; thread = 2x2 outputs via aligned float2
//          ds_reads (2 lanes/bank = conflict-free, m136); softmax without
//          max-subtraction (bench-validated R2/R5, absmax <= 0.016).
// Launched cooperatively (grid.sync between phases); if the cooperative
// launch is rejected, fall back to the identical bodies as two kernels.
// ---------------------------------------------------------------------------

__device__ __forceinline__ void phaseA_unit(
    int unit, int tid,
    const float* __restrict__ x,  const float* __restrict__ wq,
    const float* __restrict__ wk, const float* __restrict__ wv,
    float* __restrict__ qb, float* __restrict__ kb, float* __restrict__ vb)
{
    const int ptile = unit & 15;
    const int og    = ((unit >> 4) & 15) * 4;
    const int b     = unit >> 8;
    const int p     = ptile * 256 + tid;

    const float* xp  = x + (size_t)b * CIN * HW + p;
    const float* wqr = wq + og * CIN;
    const float* wkr = wk + og * CIN;
    const float* wvr = wv + og * CIN;

    float qa[4] = {0.f, 0.f, 0.f, 0.f};
    float ka[4] = {0.f, 0.f, 0.f, 0.f};
    float va[4] = {0.f, 0.f, 0.f, 0.f};

    #pragma unroll
    for (int c = 0; c < CIN; ++c) {
        const float xv = xp[(size_t)c * HW];
        #pragma unroll
        for (int oo = 0; oo < 4; ++oo) {
            qa[oo] = fmaf(xv, wqr[oo * CIN + c], qa[oo]);
            ka[oo] = fmaf(xv, wkr[oo * CIN + c], ka[oo]);
            va[oo] = fmaf(xv, wvr[oo * CIN + c], va[oo]);
        }
    }
    #pragma unroll
    for (int oo = 0; oo < 4; ++oo) {
        const size_t idx = ((size_t)b * COUT + og + oo) * HW + p;
        qb[idx] = qa[oo];
        kb[idx] = ka[oo];
        vb[idx] = va[oo];
    }
}

template <bool USE_H>
__device__ __forceinline__ void attn_tile(
    const float (*kt)[SCP], const float (*vt)[SCP],
    const float q2[2][2], const float rel[KW],
    int r0, int c0, float s[2][2], float acc[2][2])
{
    #pragma unroll
    for (int sr8 = 0; sr8 < 8; ++sr8) {       // staged rows r0 .. r0+7
        const int srow = r0 + sr8;
        float kx[8], vx[8];
        #pragma unroll
        for (int m = 0; m < 4; ++m) {
            *(float2*)&kx[2 * m] = *(const float2*)&kt[srow][c0 + 2 * m];
            *(float2*)&vx[2 * m] = *(const float2*)&vt[srow][c0 + 2 * m];
        }
        #pragma unroll
        for (int r = 0; r < 2; ++r) {
            const int i = sr8 - r;             // window row index
            if (i < 0 || i > 6) continue;      // compile-time pruned
            #pragma unroll
            for (int c = 0; c < 2; ++c) {
                #pragma unroll
                for (int j = 0; j < KW; ++j) {
                    const float relv = USE_H ? rel[i] : rel[j];
                    const float e = __builtin_amdgcn_exp2f(
                        q2[r][c] * (kx[c + j] + relv));
                    s[r][c] += e;
                    acc[r][c] = fmaf(e, vx[c + j], acc[r][c]);
                }
            }
        }
    }
}

__device__ __forceinline__ void phaseB_unit(
    int unit, int tid, float (*kt)[SCP], float (*vt)[SCP],
    const float* __restrict__ qb, const float* __restrict__ kb,
    const float* __restrict__ vb, const float* __restrict__ rel_h,
    const float* __restrict__ rel_w, float* __restrict__ out)
{
    const int rg = unit & 3;
    const int o  = (unit >> 2) & 63;
    const int b  = unit >> 8;
    const size_t plane = ((size_t)b * COUT + o) * HW;
    const int r0g = rg * TR;

    for (int idx = tid; idx < SRB * SCW; idx += 256) {
        const int sr = idx / SCW;
        const int sc = idx - sr * SCW;
        const int gr = r0g - 3 + sr;
        const int gc = sc - 3;
        float kk = 0.f, vv = 0.f;
        if (((unsigned)gr < HH) & ((unsigned)gc < WW)) {
            kk = kb[plane + (size_t)gr * WW + gc];
            vv = vb[plane + (size_t)gr * WW + gc];
        }
        kt[sr][sc] = kk;
        vt[sr][sc] = vv;
    }
    __syncthreads();

    const int cx = tid & 31;
    const int ry = tid >> 5;
    const int c0 = 2 * cx;
    const int r0 = 2 * ry;

    const bool use_h = (o < COUT / 2);             // block-uniform
    const float* rp = use_h ? (rel_h + o * KW) : (rel_w + (o - COUT / 2) * KW);
    float rel[KW];
    #pragma unroll
    for (int t = 0; t < KW; ++t) rel[t] = rp[t];

    float q2[2][2];
    #pragma unroll
    for (int r = 0; r < 2; ++r) {
        const float2 qv =
            *(const float2*)&qb[plane + (size_t)(r0g + r0 + r) * WW + c0];
        q2[r][0] = qv.x * 1.44269504088896f;       // fold log2(e)
        q2[r][1] = qv.y * 1.44269504088896f;
    }

    float s[2][2]   = {{0.f, 0.f}, {0.f, 0.f}};
    float acc[2][2] = {{0.f, 0.f}, {0.f, 0.f}};
    if (use_h) attn_tile<true >(kt, vt, q2, rel, r0, c0, s, acc);
    else       attn_tile<false>(kt, vt, q2, rel, r0, c0, s, acc);

    #pragma unroll
    for (int r = 0; r < 2; ++r) {
        float2 ov;
        ov.x = acc[r][0] * __builtin_amdgcn_rcpf(s[r][0]);
        ov.y = acc[r][1] * __builtin_amdgcn_rcpf(s[r][1]);
        *(float2*)&out[plane + (size_t)(r0g + r0 + r) * WW + c0] = ov;
    }
}

__global__ __launch_bounds__(256, 2) void fused_coop(
    const float* __restrict__ x,  const float* __restrict__ wq,
    const float* __restrict__ wk, const float* __restrict__ wv,
    const float* __restrict__ rel_h, const float* __restrict__ rel_w,
    float* __restrict__ qb, float* __restrict__ kb, float* __restrict__ vb,
    float* __restrict__ out)
{
    __shared__ float kt[SRB][SCP];
    __shared__ float vt[SRB][SCP];
    const int tid = threadIdx.x;
    const int B0  = blockIdx.x;

    phaseA_unit(2 * B0,     tid, x, wq, wk, wv, qb, kb, vb);
    phaseA_unit(2 * B0 + 1, tid, x, wq, wk, wv, qb, kb, vb);

    cg::this_grid().sync();

    phaseB_unit(2 * B0,     tid, kt, vt, qb, kb, vb, rel_h, rel_w, out);
    __syncthreads();                        // protect LDS before restage
    phaseB_unit(2 * B0 + 1, tid, kt, vt, qb, kb, vb, rel_h, rel_w, out);
}

__global__ __launch_bounds__(256, 2) void projK(
    const float* __restrict__ x,  const float* __restrict__ wq,
    const float* __restrict__ wk, const float* __restrict__ wv,
    float* __restrict__ qb, float* __restrict__ kb, float* __restrict__ vb)
{
    phaseA_unit(2 * blockIdx.x,     threadIdx.x, x, wq, wk, wv, qb, kb, vb);
    phaseA_unit(2 * blockIdx.x + 1, threadIdx.x, x, wq, wk, wv, qb, kb, vb);
}

__global__ __launch_bounds__(256, 2) void attnK(
    const float* __restrict__ qb, const float* __restrict__ kb,
    const float* __restrict__ vb, const float* __restrict__ rel_h,
    const float* __restrict__ rel_w, float* __restrict__ out)
{
    __shared__ float kt[SRB][SCP];
    __shared__ float vt[SRB][SCP];
    phaseB_unit(2 * blockIdx.x,     threadIdx.x, kt, vt, qb, kb, vb, rel_h, rel_w, out);
    __syncthreads();
    phaseB_unit(2 * blockIdx.x + 1, threadIdx.x, kt, vt, qb, kb, vb, rel_h, rel_w, out);
}

extern "C" void kernel_launch(void* const* d_in, const int* in_sizes, int n_in,
                              void* d_out, int out_size, void* d_ws, size_t ws_size,
                              hipStream_t stream) {
    const float* x     = (const float*)d_in[0];
    const float* wq    = (const float*)d_in[1];
    const float* wk    = (const float*)d_in[2];
    const float* wv    = (const float*)d_in[3];
    const float* rel_h = (const float*)d_in[4];
    const float* rel_w = (const float*)d_in[5];
    float* out = (float*)d_out;

    float* qb = (float*)d_ws;                  // 3 x 4 MB in d_ws
    float* kb = qb + (size_t)BB * COUT * HW;
    float* vb = kb + (size_t)BB * COUT * HW;

    void* args[] = {(void*)&x, (void*)&wq, (void*)&wk, (void*)&wv,
                    (void*)&rel_h, (void*)&rel_w,
                    (void*)&qb, (void*)&kb, (void*)&vb, (void*)&out};

    hipError_t rc = hipLaunchCooperativeKernel(
        (void*)fused_coop, dim3(512), dim3(256), args, 0, stream);
    if (rc != hipSuccess) {
        (void)hipGetLastError();               // clear sticky error
        projK<<<dim3(512), dim3(256), 0, stream>>>(x, wq, wk, wv, qb, kb, vb);
        attnK<<<dim3(512), dim3(256), 0, stream>>>(qb, kb, vb, rel_h, rel_w, out);
    }
}

// Round 8
// 40.449 us; speedup vs baseline: 3.3536x; 3.3536x over previous
//
#include <hip/hip_runtime.h>

#define KW   7
#define CIN  64
#define COUT 64
#define HH   64
#define WW   64
#define BB   4
#define HW   (HH * WW)

// attention tile geometry
#define TR   16            // output rows per block
#define SRB  (TR + 6)      // 22 staged k/v rows
#define SCW  70            // staged cols: 3 zero + 64 + 3 zero
#define SCP  74            // padded LDS row stride (dwords)

// ---------------------------------------------------------------------------
// K1: q/k/v 1x1-conv projection (R2's proven mapping).
// Block (ptile, og, b): thread = 1 pixel x 4 channels; weights block-uniform
// (scalarized); x loads coalesced 256B/wave; each x value feeds 12 FMAs.
// Padded positions of k_full/v_full are exactly 0 (1x1 conv of zero padding,
// no bias) -> K2 synthesizes zeros in LDS. ~3 us model (VALU+L2).
// ---------------------------------------------------------------------------
__global__ __launch_bounds__(256) void projK(
    const float* __restrict__ x,  const float* __restrict__ wq,
    const float* __restrict__ wk, const float* __restrict__ wv,
    float* __restrict__ qb, float* __restrict__ kb, float* __restrict__ vb)
{
    const int tid = threadIdx.x;
    const int og  = blockIdx.y * 4;
    const int b   = blockIdx.z;
    const int p   = blockIdx.x * 256 + tid;

    const float* xp  = x + (size_t)b * CIN * HW + p;
    const float* wqr = wq + og * CIN;
    const float* wkr = wk + og * CIN;
    const float* wvr = wv + og * CIN;

    float qa[4] = {0.f, 0.f, 0.f, 0.f};
    float ka[4] = {0.f, 0.f, 0.f, 0.f};
    float va[4] = {0.f, 0.f, 0.f, 0.f};

    #pragma unroll
    for (int c = 0; c < CIN; ++c) {
        const float xv = xp[(size_t)c * HW];
        #pragma unroll
        for (int oo = 0; oo < 4; ++oo) {
            qa[oo] = fmaf(xv, wqr[oo * CIN + c], qa[oo]);
            ka[oo] = fmaf(xv, wkr[oo * CIN + c], ka[oo]);
            va[oo] = fmaf(xv, wvr[oo * CIN + c], va[oo]);
        }
    }
    #pragma unroll
    for (int oo = 0; oo < 4; ++oo) {
        const size_t idx = ((size_t)b * COUT + og + oo) * HW + p;
        qb[idx] = qa[oo];
        kb[idx] = ka[oo];
        vb[idx] = va[oo];
    }
}

// ---------------------------------------------------------------------------
// K2: 7x7 local attention, 2x2 register-blocked.
// Block = one (b,o) plane x 16 rows, 256 threads = 32 colpairs x 8 rowpairs.
// k/v staged once into a 22x74-stride LDS tile with zero borders. Each thread
// streams its 8 window rows as aligned float2 (ds_read_b64): 64 b64 for 4
// outputs = 16 LDS instr/output (vs 120 b32 in the scalar version — the
// measured 18.6 us/CU LDS-issue term). Softmax without max-subtraction
// (bench-validated R2/R5/R7, absmax <= 0.016); rel row/col select hoisted
// via template on block-uniform use_h.
// ---------------------------------------------------------------------------
template <bool USE_H>
__device__ __forceinline__ void attn_tile(
    const float (*kt)[SCP], const float (*vt)[SCP],
    const float q2[2][2], const float rel[KW],
    int r0, int c0, float s[2][2], float acc[2][2])
{
    #pragma unroll
    for (int sr8 = 0; sr8 < 8; ++sr8) {       // staged rows r0 .. r0+7
        const int srow = r0 + sr8;
        float kx[8], vx[8];
        #pragma unroll
        for (int m = 0; m < 4; ++m) {
            *(float2*)&kx[2 * m] = *(const float2*)&kt[srow][c0 + 2 * m];
            *(float2*)&vx[2 * m] = *(const float2*)&vt[srow][c0 + 2 * m];
        }
        #pragma unroll
        for (int r = 0; r < 2; ++r) {
            const int i = sr8 - r;             // window row index
            if (i < 0 || i > 6) continue;      // compile-time pruned
            #pragma unroll
            for (int c = 0; c < 2; ++c) {
                #pragma unroll
                for (int j = 0; j < KW; ++j) {
                    const float relv = USE_H ? rel[i] : rel[j];
                    const float e = __builtin_amdgcn_exp2f(
                        q2[r][c] * (kx[c + j] + relv));
                    s[r][c] += e;
                    acc[r][c] = fmaf(e, vx[c + j], acc[r][c]);
                }
            }
        }
    }
}

__global__ __launch_bounds__(256) void attnK(
    const float* __restrict__ qb, const float* __restrict__ kb,
    const float* __restrict__ vb, const float* __restrict__ rel_h,
    const float* __restrict__ rel_w, float* __restrict__ out)
{
    __shared__ float kt[SRB][SCP];
    __shared__ float vt[SRB][SCP];

    const int tid = threadIdx.x;
    const int rg  = blockIdx.x;               // 0..3 (16-row group)
    const int o   = blockIdx.y;
    const int b   = blockIdx.z;
    const size_t plane = ((size_t)b * COUT + o) * HW;
    const int r0g = rg * TR;

    for (int idx = tid; idx < SRB * SCW; idx += 256) {
        const int sr = idx / SCW;
        const int sc = idx - sr * SCW;
        const int gr = r0g - 3 + sr;
        const int gc = sc - 3;
        float kk = 0.f, vv = 0.f;
        if (((unsigned)gr < HH) & ((unsigned)gc < WW)) {
            kk = kb[plane + (size_t)gr * WW + gc];
            vv = vb[plane + (size_t)gr * WW + gc];
        }
        kt[sr][sc] = kk;
        vt[sr][sc] = vv;
    }
    __syncthreads();

    const int cx = tid & 31;                  // column pair
    const int ry = tid >> 5;                  // row pair 0..7
    const int c0 = 2 * cx;
    const int r0 = 2 * ry;

    const bool use_h = (o < COUT / 2);        // block-uniform
    const float* rp = use_h ? (rel_h + o * KW) : (rel_w + (o - COUT / 2) * KW);
    float rel[KW];
    #pragma unroll
    for (int t = 0; t < KW; ++t) rel[t] = rp[t];

    float q2[2][2];
    #pragma unroll
    for (int r = 0; r < 2; ++r) {
        const float2 qv =
            *(const float2*)&qb[plane + (size_t)(r0g + r0 + r) * WW + c0];
        q2[r][0] = qv.x * 1.44269504088896f;  // fold log2(e)
        q2[r][1] = qv.y * 1.44269504088896f;
    }

    float s[2][2]   = {{0.f, 0.f}, {0.f, 0.f}};
    float acc[2][2] = {{0.f, 0.f}, {0.f, 0.f}};
    if (use_h) attn_tile<true >(kt, vt, q2, rel, r0, c0, s, acc);
    else       attn_tile<false>(kt, vt, q2, rel, r0, c0, s, acc);

    #pragma unroll
    for (int r = 0; r < 2; ++r) {
        float2 ov;
        ov.x = acc[r][0] * __builtin_amdgcn_rcpf(s[r][0]);
        ov.y = acc[r][1] * __builtin_amdgcn_rcpf(s[r][1]);
        *(float2*)&out[plane + (size_t)(r0g + r0 + r) * WW + c0] = ov;
    }
}

extern "C" void kernel_launch(void* const* d_in, const int* in_sizes, int n_in,
                              void* d_out, int out_size, void* d_ws, size_t ws_size,
                              hipStream_t stream) {
    const float* x     = (const float*)d_in[0];
    const float* wq    = (const float*)d_in[1];
    const float* wk    = (const float*)d_in[2];
    const float* wv    = (const float*)d_in[3];
    const float* rel_h = (const float*)d_in[4];
    const float* rel_w = (const float*)d_in[5];
    float* out = (float*)d_out;

    float* qb = (float*)d_ws;                  // 3 x 4 MB in d_ws
    float* kb = qb + (size_t)BB * COUT * HW;
    float* vb = kb + (size_t)BB * COUT * HW;

    dim3 g1(HW / 256, COUT / 4, BB);           // (16, 16, 4) = 1024 blocks
    projK<<<g1, 256, 0, stream>>>(x, wq, wk, wv, qb, kb, vb);

    dim3 g2(HH / TR, COUT, BB);                // (4, 64, 4) = 1024 blocks
    attnK<<<g2, 256, 0, stream>>>(qb, kb, vb, rel_h, rel_w, out);
}

// Round 9
// 27.649 us; speedup vs baseline: 4.9061x; 1.4629x over previous
//
#include <hip/hip_runtime.h>

#define KW   7
#define CIN  64
#define COUT 64
#define HH   64
#define WW   64
#define BB   4
#define HW   (HH * WW)

typedef __attribute__((ext_vector_type(8))) short short8v;  // 8 bf16
typedef __attribute__((ext_vector_type(4))) float f32x4;

__device__ __forceinline__ unsigned pack_bf16(float lo, float hi) {
    unsigned a = __builtin_bit_cast(unsigned, lo);
    unsigned b = __builtin_bit_cast(unsigned, hi);
    a = (a + 0x7fffu + ((a >> 16) & 1u)) >> 16;   // RNE f32->bf16
    b = (b + 0x7fffu + ((b >> 16) & 1u)) >> 16;
    return a | (b << 16);
}

// ---------------------------------------------------------------------------
// K1: q/k/v projection as bf16 MFMA GEMM — R5's verified math (absmax 0.068),
// re-gridded for occupancy: 1024 blocks (4/CU) instead of 256 (1/CU, which
// was latency-bound at ~10us). Block = (64-px tile, M-quarter of 48 rows, b).
// Stacked W rows 0-63=wq, 64-127=wk, 128-191=wv. Each 16-row m-tile lies
// fully inside one matrix (48=3x16, 64%16=0). A/B frags share the same
// lane->k map (guessed permutation cancels); C/D map is HW-verified
// (col=lane&15, row=(lane>>4)*4+reg, m89).
// ---------------------------------------------------------------------------
#define LWROW 36   // dwords per LDS row (32 bf16-pairs padded)

__global__ __launch_bounds__(256) void projK(
    const float* __restrict__ x,  const float* __restrict__ wq,
    const float* __restrict__ wk, const float* __restrict__ wv,
    float* __restrict__ qb, float* __restrict__ kb, float* __restrict__ vb)
{
    __shared__ unsigned lw[48 * LWROW];    // W quarter as bf16 pairs
    __shared__ unsigned xt[64 * LWROW];    // x tile, pixel-major bf16 pairs

    const int tid = threadIdx.x;
    const int p0  = blockIdx.x * 64;       // pixel tile within batch
    const int mq  = blockIdx.y;            // M-quarter: rows mq*48..mq*48+47
    const int b   = blockIdx.z;

    // Stage W quarter (48 x 64 f32 -> bf16 pairs).
    const float* wsel[3] = {wq, wk, wv};
    for (int idx = tid; idx < 48 * 32; idx += 256) {
        const int r  = idx >> 5;               // 0..47
        const int dw = idx & 31;
        const int g  = mq * 48 + r;            // global stacked row
        const float* wr = wsel[g >> 6] + (g & 63) * CIN + dw * 2;
        lw[r * LWROW + dw] = pack_bf16(wr[0], wr[1]);
    }
    // Stage x tile (64 px x 64 ch), pixel-major.
    {
        const int p = tid & 63, grp = tid >> 6;
        const float* xb = x + (size_t)b * CIN * HW + p0 + p;
        #pragma unroll
        for (int d = 0; d < 8; ++d) {
            const int dw = grp * 8 + d;
            xt[p * LWROW + dw] =
                pack_bf16(xb[(size_t)(2 * dw) * HW], xb[(size_t)(2 * dw + 1) * HW]);
        }
    }
    __syncthreads();

    const int lane = tid & 63;
    const int wid  = tid >> 6;             // wave = 16-px column tile
    const int col  = lane & 15;
    const int lg   = lane >> 4;
    const int n0   = wid * 16;

    short8v bfrag[2];
    #pragma unroll
    for (int kc = 0; kc < 2; ++kc)
        bfrag[kc] = *(const short8v*)&xt[(n0 + col) * LWROW + kc * 16 + lg * 4];

    float* osel[3] = {qb, kb, vb};
    #pragma unroll
    for (int t = 0; t < 3; ++t) {                  // 3 m-tiles per quarter
        f32x4 acc = {0.f, 0.f, 0.f, 0.f};
        #pragma unroll
        for (int kc = 0; kc < 2; ++kc) {
            const short8v afrag =
                *(const short8v*)&lw[(t * 16 + col) * LWROW + kc * 16 + lg * 4];
            acc = __builtin_amdgcn_mfma_f32_16x16x32_bf16(afrag, bfrag[kc], acc, 0, 0, 0);
        }
        const int g0  = mq * 48 + t * 16;          // tile's global row base
        const int mat = g0 >> 6;                   // 0=q,1=k,2=v
        const int chb = (g0 & 63) + lg * 4;
        float* dst = osel[mat] + ((size_t)b * COUT + chb) * HW + p0 + n0 + col;
        #pragma unroll
        for (int r = 0; r < 4; ++r) dst[(size_t)r * HW] = acc[r];
    }
}

// ---------------------------------------------------------------------------
// K2: R2's measured-best attention, single change: k,v interleaved as float2
// in LDS so each window position is ONE ds_read_b64 (49/thread) instead of
// two ds_read_b32 (98/thread). LDS is the CU-shared bottleneck pipe
// (~15us -> ~9us model). Banks: adjacent lanes 2 dwords apart = 2 lanes/bank
// (free, m136). Everything else identical to R2 (4096 blocks, 1 out/thread,
// no-max softmax — bench-validated absmax <= 0.016).
// ---------------------------------------------------------------------------
__global__ __launch_bounds__(256) void attnK(
    const float* __restrict__ qb, const float* __restrict__ kb,
    const float* __restrict__ vb, const float* __restrict__ rel_h,
    const float* __restrict__ rel_w, float* __restrict__ out)
{
    __shared__ float2 kv[10][70];

    const int tx = threadIdx.x;               // w: 0..63 (lane)
    const int ty = threadIdx.y;               // row in tile: 0..3
    const int h0 = blockIdx.x * 4;
    const int o  = blockIdx.y;
    const int b  = blockIdx.z;
    const size_t plane = ((size_t)b * COUT + o) * HW;

    // Stage rows h0-3 .. h0+6, cols -3..66, zeros outside interior.
    for (int idx = ty * 64 + tx; idx < 10 * 70; idx += 256) {
        const int rr = idx / 70;
        const int sc = idx - rr * 70;
        const int gr = h0 - 3 + rr;
        const int gc = sc - 3;
        float kk = 0.f, vv = 0.f;
        if (((unsigned)gr < HH) & ((unsigned)gc < WW)) {
            kk = kb[plane + (size_t)gr * WW + gc];
            vv = vb[plane + (size_t)gr * WW + gc];
        }
        kv[rr][sc] = make_float2(kk, vv);
    }
    __syncthreads();

    const float q  = qb[plane + (size_t)(h0 + ty) * WW + tx];
    const float q2 = q * 1.44269504088896f;   // fold log2(e)

    const bool use_h = (o < COUT / 2);        // block-uniform
    const float* rp = use_h ? (rel_h + o * KW) : (rel_w + (o - COUT / 2) * KW);
    float qadd[KW];
    #pragma unroll
    for (int t = 0; t < KW; ++t) qadd[t] = q2 * rp[t];

    float s = 0.f, acc = 0.f;
    if (use_h) {
        #pragma unroll
        for (int i = 0; i < KW; ++i) {
            #pragma unroll
            for (int j = 0; j < KW; ++j) {
                const float2 kvv = kv[ty + i][tx + j];
                const float e = __builtin_amdgcn_exp2f(fmaf(q2, kvv.x, qadd[i]));
                s += e;
                acc = fmaf(e, kvv.y, acc);
            }
        }
    } else {
        #pragma unroll
        for (int i = 0; i < KW; ++i) {
            #pragma unroll
            for (int j = 0; j < KW; ++j) {
                const float2 kvv = kv[ty + i][tx + j];
                const float e = __builtin_amdgcn_exp2f(fmaf(q2, kvv.x, qadd[j]));
                s += e;
                acc = fmaf(e, kvv.y, acc);
            }
        }
    }

    out[plane + (size_t)(h0 + ty) * WW + tx] = acc * __builtin_amdgcn_rcpf(s);
}

extern "C" void kernel_launch(void* const* d_in, const int* in_sizes, int n_in,
                              void* d_out, int out_size, void* d_ws, size_t ws_size,
                              hipStream_t stream) {
    const float* x     = (const float*)d_in[0];
    const float* wq    = (const float*)d_in[1];
    const float* wk    = (const float*)d_in[2];
    const float* wv    = (const float*)d_in[3];
    const float* rel_h = (const float*)d_in[4];
    const float* rel_w = (const float*)d_in[5];
    float* out = (float*)d_out;

    float* qb = (float*)d_ws;                 // 3 x 4 MB in d_ws
    float* kb = qb + (size_t)BB * COUT * HW;
    float* vb = kb + (size_t)BB * COUT * HW;

    dim3 g1(HW / 64, 4, BB);                  // (64, 4, 4) = 1024 blocks
    projK<<<g1, 256, 0, stream>>>(x, wq, wk, wv, qb, kb, vb);

    dim3 g2(HH / 4, COUT, BB);                // (16, 64, 4) = 4096 blocks
    dim3 b2(64, 4);
    attnK<<<g2, b2, 0, stream>>>(qb, kb, vb, rel_h, rel_w, out);
}

// Round 10
// 27.112 us; speedup vs baseline: 5.0033x; 1.0198x over previous
//
#include <hip/hip_runtime.h>

#define KW   7
#define CIN  64
#define COUT 64
#define HH   64
#define WW   64
#define BB   4
#define HW   (HH * WW)

typedef __attribute__((ext_vector_type(8))) short short8v;  // 8 bf16
typedef __attribute__((ext_vector_type(4))) float f32x4;

__device__ __forceinline__ unsigned pack_bf16(float lo, float hi) {
    unsigned a = __builtin_bit_cast(unsigned, lo);
    unsigned b = __builtin_bit_cast(unsigned, hi);
    a = (a + 0x7fffu + ((a >> 16) & 1u)) >> 16;   // RNE f32->bf16
    b = (b + 0x7fffu + ((b >> 16) & 1u)) >> 16;
    return a | (b << 16);
}

// ---------------------------------------------------------------------------
// K1: q/k/v projection as bf16 MFMA GEMM — UNCHANGED from R9 (27.6us
// baseline, absmax 0.068). 1024 blocks (4/CU). Block = (64-px tile,
// M-quarter of 48 stacked-W rows, b). A/B frags share the same lane->k map
// (guessed permutation cancels); C/D map is HW-verified (m89).
// ---------------------------------------------------------------------------
#define LWROW 36   // dwords per LDS row (32 bf16-pairs padded)

__global__ __launch_bounds__(256) void projK(
    const float* __restrict__ x,  const float* __restrict__ wq,
    const float* __restrict__ wk, const float* __restrict__ wv,
    float* __restrict__ qb, float* __restrict__ kb, float* __restrict__ vb)
{
    __shared__ unsigned lw[48 * LWROW];    // W quarter as bf16 pairs
    __shared__ unsigned xt[64 * LWROW];    // x tile, pixel-major bf16 pairs

    const int tid = threadIdx.x;
    const int p0  = blockIdx.x * 64;       // pixel tile within batch
    const int mq  = blockIdx.y;            // M-quarter: rows mq*48..mq*48+47
    const int b   = blockIdx.z;

    const float* wsel[3] = {wq, wk, wv};
    for (int idx = tid; idx < 48 * 32; idx += 256) {
        const int r  = idx >> 5;
        const int dw = idx & 31;
        const int g  = mq * 48 + r;
        const float* wr = wsel[g >> 6] + (g & 63) * CIN + dw * 2;
        lw[r * LWROW + dw] = pack_bf16(wr[0], wr[1]);
    }
    {
        const int p = tid & 63, grp = tid >> 6;
        const float* xb = x + (size_t)b * CIN * HW + p0 + p;
        #pragma unroll
        for (int d = 0; d < 8; ++d) {
            const int dw = grp * 8 + d;
            xt[p * LWROW + dw] =
                pack_bf16(xb[(size_t)(2 * dw) * HW], xb[(size_t)(2 * dw + 1) * HW]);
        }
    }
    __syncthreads();

    const int lane = tid & 63;
    const int wid  = tid >> 6;
    const int col  = lane & 15;
    const int lg   = lane >> 4;
    const int n0   = wid * 16;

    short8v bfrag[2];
    #pragma unroll
    for (int kc = 0; kc < 2; ++kc)
        bfrag[kc] = *(const short8v*)&xt[(n0 + col) * LWROW + kc * 16 + lg * 4];

    float* osel[3] = {qb, kb, vb};
    #pragma unroll
    for (int t = 0; t < 3; ++t) {
        f32x4 acc = {0.f, 0.f, 0.f, 0.f};
        #pragma unroll
        for (int kc = 0; kc < 2; ++kc) {
            const short8v afrag =
                *(const short8v*)&lw[(t * 16 + col) * LWROW + kc * 16 + lg * 4];
            acc = __builtin_amdgcn_mfma_f32_16x16x32_bf16(afrag, bfrag[kc], acc, 0, 0, 0);
        }
        const int g0  = mq * 48 + t * 16;
        const int mat = g0 >> 6;
        const int chb = (g0 & 63) + lg * 4;
        float* dst = osel[mat] + ((size_t)b * COUT + chb) * HW + p0 + n0 + col;
        #pragma unroll
        for (int r = 0; r < 4; ++r) dst[(size_t)r * HW] = acc[r];
    }
}

// ---------------------------------------------------------------------------
// K2: 7x7 local attention, 2-row register blocking inside R9's proven
// small-block geometry. Block (64,4) covers 8 output rows of one (b,o)
// plane (2 rows/thread, same column); tile 14x70 float2; grid 2048 blocks
// (8/CU, 32 waves/CU). Each loaded row of 7 float2 feeds BOTH outputs:
// 56 b64 / 2 outputs = 224 B/output vs R9's 392 (LDS pipe is BW-bound at
// ~85 B/cy/CU). Softmax without max-subtraction (bench-validated, absmax
// <= 0.016 f32-path); rel row/col select via template on block-uniform o.
// ---------------------------------------------------------------------------
#define TRO  8             // output rows per block
#define SRO  (TRO + 6)     // 14 staged rows

template <bool USE_H>
__device__ __forceinline__ void attn_rows(
    const float2 (*kv)[70], const float q2[2], const float qadd[2][KW],
    int tx, int r0, float s[2], float acc[2])
{
    #pragma unroll
    for (int rr = 0; rr < 8; ++rr) {          // tile rows r0 .. r0+7
        float2 kvx[KW];
        #pragma unroll
        for (int j = 0; j < KW; ++j) kvx[j] = kv[r0 + rr][tx + j];

        if (rr <= 6) {                         // output 0: window row i = rr
            #pragma unroll
            for (int j = 0; j < KW; ++j) {
                const float e = __builtin_amdgcn_exp2f(
                    fmaf(q2[0], kvx[j].x, qadd[0][USE_H ? rr : j]));
                s[0] += e;
                acc[0] = fmaf(e, kvx[j].y, acc[0]);
            }
        }
        if (rr >= 1) {                         // output 1: window row i = rr-1
            #pragma unroll
            for (int j = 0; j < KW; ++j) {
                const float e = __builtin_amdgcn_exp2f(
                    fmaf(q2[1], kvx[j].x, qadd[1][USE_H ? (rr - 1) : j]));
                s[1] += e;
                acc[1] = fmaf(e, kvx[j].y, acc[1]);
            }
        }
    }
}

__global__ __launch_bounds__(256) void attnK(
    const float* __restrict__ qb, const float* __restrict__ kb,
    const float* __restrict__ vb, const float* __restrict__ rel_h,
    const float* __restrict__ rel_w, float* __restrict__ out)
{
    __shared__ float2 kv[SRO][70];

    const int tx = threadIdx.x;               // w: 0..63 (lane)
    const int ty = threadIdx.y;               // row pair: 0..3
    const int h0 = blockIdx.x * TRO;
    const int o  = blockIdx.y;
    const int b  = blockIdx.z;
    const size_t plane = ((size_t)b * COUT + o) * HW;

    // Stage rows h0-3 .. h0+10, cols -3..66, zeros outside the interior.
    for (int idx = ty * 64 + tx; idx < SRO * 70; idx += 256) {
        const int rr = idx / 70;
        const int sc = idx - rr * 70;
        const int gr = h0 - 3 + rr;
        const int gc = sc - 3;
        float kk = 0.f, vv = 0.f;
        if (((unsigned)gr < HH) & ((unsigned)gc < WW)) {
            kk = kb[plane + (size_t)gr * WW + gc];
            vv = vb[plane + (size_t)gr * WW + gc];
        }
        kv[rr][sc] = make_float2(kk, vv);
    }
    __syncthreads();

    const int r0 = 2 * ty;                    // local output rows r0, r0+1

    float q2[2];
    #pragma unroll
    for (int r = 0; r < 2; ++r)
        q2[r] = qb[plane + (size_t)(h0 + r0 + r) * WW + tx] * 1.44269504088896f;

    const bool use_h = (o < COUT / 2);        // block-uniform
    const float* rp = use_h ? (rel_h + o * KW) : (rel_w + (o - COUT / 2) * KW);
    float qadd[2][KW];
    #pragma unroll
    for (int t = 0; t < KW; ++t) {
        const float rv = rp[t];
        qadd[0][t] = q2[0] * rv;
        qadd[1][t] = q2[1] * rv;
    }

    float s[2]   = {0.f, 0.f};
    float acc[2] = {0.f, 0.f};
    if (use_h) attn_rows<true >(kv, q2, qadd, tx, r0, s, acc);
    else       attn_rows<false>(kv, q2, qadd, tx, r0, s, acc);

    #pragma unroll
    for (int r = 0; r < 2; ++r)
        out[plane + (size_t)(h0 + r0 + r) * WW + tx] =
            acc[r] * __builtin_amdgcn_rcpf(s[r]);
}

extern "C" void kernel_launch(void* const* d_in, const int* in_sizes, int n_in,
                              void* d_out, int out_size, void* d_ws, size_t ws_size,
                              hipStream_t stream) {
    const float* x     = (const float*)d_in[0];
    const float* wq    = (const float*)d_in[1];
    const float* wk    = (const float*)d_in[2];
    const float* wv    = (const float*)d_in[3];
    const float* rel_h = (const float*)d_in[4];
    const float* rel_w = (const float*)d_in[5];
    float* out = (float*)d_out;

    float* qb = (float*)d_ws;                 // 3 x 4 MB in d_ws
    float* kb = qb + (size_t)BB * COUT * HW;
    float* vb = kb + (size_t)BB * COUT * HW;

    dim3 g1(HW / 64, 4, BB);                  // (64, 4, 4) = 1024 blocks
    projK<<<g1, 256, 0, stream>>>(x, wq, wk, wv, qb, kb, vb);

    dim3 g2(HH / TRO, COUT, BB);              // (8, 64, 4) = 2048 blocks
    dim3 b2(64, 4);
    attnK<<<g2, b2, 0, stream>>>(qb, kb, vb, rel_h, rel_w, out);
}